// Round 1
// baseline (154.997 us; speedup 1.0000x reference)
//
#include <hip/hip_runtime.h>
#include <hip/hip_bf16.h>

// TripletLoss, N=8192, D=256 fp32, targets in [0,128).
// out[0] = mean(relu(dist_ap - dist_an + 0.3)), out[1] = mean(dist_an > dist_ap)
// dist = sqrt(clip(sq_i + sq_j - 2 dot, 1e-12)); sqrt deferred (monotone);
// d2 > 0 so uint-bit order == float order -> atomicMax/Min on unsigned.
//
// R6: drop LDS staging entirely. K=256 means only 8 k-phases per block; the
// R5 structure paid a __syncthreads (vmcnt(0) drain of global_load_lds) per
// phase against L2 latency -> latency convoy (MfmaUtil 9%, 75us for 2.2us of
// MFMA). The 16x16x32 bf16 fragment is row-major 16B/lane (lane l15 = row,
// quad = k-slice), so fragments load DIRECTLY global->VGPR: zero k-loop
// barriers, zero staging LDS, register double-buffer, compiler emits counted
// vmcnt. L2 traffic 266->532 MB (no cross-wave sharing; L1 recovers part) =
// ~15us floor, far under the 75us we pay for barrier drains.

#define N 8192
#define D 256
#define MARGIN 0.3f
#define NBLK 2080  // 64*65/2 lower-triangle 128x128 tiles

typedef __bf16  bf16x8  __attribute__((ext_vector_type(8)));
typedef float   floatx4 __attribute__((ext_vector_type(4)));

// ---------------- Kernel A: bf16 cast + row sq-norms + init ------------------
__global__ __launch_bounds__(256) void prep_kernel(
    const float* __restrict__ X, unsigned short* __restrict__ Xb,
    float* __restrict__ sq, unsigned* __restrict__ pmax, unsigned* __restrict__ nmin) {
  const int t = threadIdx.x;
  const int lane = t & 63, wave = t >> 6;
  const int row0 = blockIdx.x * 8 + wave * 2;
#pragma unroll
  for (int r = 0; r < 2; ++r) {
    const int row = row0 + r;
    float4 v = *reinterpret_cast<const float4*>(X + (size_t)row * D + lane * 4);
    ushort4 h;
    {
      __hip_bfloat16 b0 = __float2bfloat16(v.x), b1 = __float2bfloat16(v.y);
      __hip_bfloat16 b2 = __float2bfloat16(v.z), b3 = __float2bfloat16(v.w);
      h.x = *reinterpret_cast<unsigned short*>(&b0);
      h.y = *reinterpret_cast<unsigned short*>(&b1);
      h.z = *reinterpret_cast<unsigned short*>(&b2);
      h.w = *reinterpret_cast<unsigned short*>(&b3);
    }
    *reinterpret_cast<ushort4*>(Xb + (size_t)row * D + lane * 4) = h;
    float s = v.x * v.x + v.y * v.y + v.z * v.z + v.w * v.w;
#pragma unroll
    for (int o = 32; o > 0; o >>= 1) s += __shfl_down(s, o);
    if (lane == 0) {
      sq[row] = s;
      pmax[row] = 0u;
      nmin[row] = 0x7F800000u;  // +inf
    }
  }
}

// ---------------- Kernel B: triangular tiles, reg-direct fragments -----------
__global__ __launch_bounds__(256) void tile_kernel(
    const unsigned short* __restrict__ Xb, const float* __restrict__ sq,
    const int* __restrict__ tgt, unsigned* __restrict__ pmax, unsigned* __restrict__ nmin) {
  // lower-triangle decode: bi -> (by >= bx)
  const int bi = blockIdx.x;
  int by = (int)((sqrtf(8.0f * (float)bi + 1.0f) - 1.0f) * 0.5f);
  while ((by + 1) * (by + 2) / 2 <= bi) ++by;
  while (by * (by + 1) / 2 > bi) --by;
  const int bx = bi - by * (by + 1) / 2;
  const int rowBase = by * 128, colBase = bx * 128;

  const int t = threadIdx.x;
  const int lane = t & 63, wave = t >> 6;
  const int wy = wave >> 1, wx = wave & 1;
  const int quad = lane >> 4, l15 = lane & 15;

  __shared__ float sqr[128], sqc[128];
  __shared__ int   tr[128], tc[128];
  __shared__ unsigned pmL[128], nmL[128], pmLc[128], nmLc[128];

  if (t < 128) {
    sqr[t] = sq[rowBase + t]; tr[t] = tgt[rowBase + t];
    pmL[t] = 0u; nmL[t] = 0x7F800000u;
  } else {
    int u = t - 128;
    sqc[u] = sq[colBase + u]; tc[u] = tgt[colBase + u];
    pmLc[u] = 0u; nmLc[u] = 0x7F800000u;
  }

  // fragment base offsets (elements). 16x16x32 bf16 A/B fragment is
  // row-major 16B per lane: lane l15 = row-within-16-tile, quad = 8-elem
  // k-slice. Per-phase advance kk*32 elems = 64B folds into the load's
  // 13-bit immediate offset (max 448B) -> zero address math in the loop.
  int aOff[4], bOff[4];
#pragma unroll
  for (int mi = 0; mi < 4; ++mi)
    aOff[mi] = (rowBase + wy * 64 + mi * 16 + l15) * D + quad * 8;
#pragma unroll
  for (int nj = 0; nj < 4; ++nj)
    bOff[nj] = (colBase + wx * 64 + nj * 16 + l15) * D + quad * 8;

  // register double-buffer: load phase kk+1 while MFMAing phase kk.
  // No barriers -> compiler emits counted vmcnt, loads stay in flight.
  bf16x8 a[2][4], b[2][4];
#pragma unroll
  for (int mi = 0; mi < 4; ++mi)
    a[0][mi] = *reinterpret_cast<const bf16x8*>(Xb + aOff[mi]);
#pragma unroll
  for (int nj = 0; nj < 4; ++nj)
    b[0][nj] = *reinterpret_cast<const bf16x8*>(Xb + bOff[nj]);

  floatx4 acc[4][4];
#pragma unroll
  for (int mi = 0; mi < 4; ++mi)
#pragma unroll
    for (int nj = 0; nj < 4; ++nj)
      acc[mi][nj] = (floatx4){0.f, 0.f, 0.f, 0.f};

#pragma unroll
  for (int kk = 0; kk < 8; ++kk) {
    const int cur = kk & 1;
    if (kk < 7) {
      const int nxt = cur ^ 1;
      const int ko = (kk + 1) * 32;
#pragma unroll
      for (int mi = 0; mi < 4; ++mi)
        a[nxt][mi] = *reinterpret_cast<const bf16x8*>(Xb + aOff[mi] + ko);
#pragma unroll
      for (int nj = 0; nj < 4; ++nj)
        b[nxt][nj] = *reinterpret_cast<const bf16x8*>(Xb + bOff[nj] + ko);
    }
#pragma unroll
    for (int mi = 0; mi < 4; ++mi)
#pragma unroll
      for (int nj = 0; nj < 4; ++nj)
        acc[mi][nj] = __builtin_amdgcn_mfma_f32_16x16x32_bf16(a[cur][mi], b[cur][nj], acc[mi][nj], 0, 0, 0);
  }

  __syncthreads();  // sqr/sqc/tr/tc loads + pmL/nmL inits visible to all

  // ---- two-sided epilogue on clipped d2 ----
  float sqc_l[4]; int tc_l[4];
#pragma unroll
  for (int nj = 0; nj < 4; ++nj) {
    int jl = wx * 64 + nj * 16 + l15;
    sqc_l[nj] = sqc[jl];
    tc_l[nj]  = tc[jl];
  }

  float pm[16], nm[16], cmP[4], cmN[4];
#pragma unroll
  for (int s = 0; s < 16; ++s) { pm[s] = 0.f; nm[s] = __builtin_huge_valf(); }
#pragma unroll
  for (int nj = 0; nj < 4; ++nj) { cmP[nj] = 0.f; cmN[nj] = __builtin_huge_valf(); }

#pragma unroll
  for (int mi = 0; mi < 4; ++mi) {
#pragma unroll
    for (int r = 0; r < 4; ++r) {
      int il = wy * 64 + mi * 16 + quad * 4 + r;
      float si = sqr[il];
      int   ti = tr[il];
      int   s  = mi * 4 + r;
#pragma unroll
      for (int nj = 0; nj < 4; ++nj) {
        float d2 = fmaxf(fmaf(-2.f, acc[mi][nj][r], si + sqc_l[nj]), 1e-12f);
        bool same = (ti == tc_l[nj]);
        float selP = same ? d2 : 0.f;                      // no-op for max
        float selN = same ? __builtin_huge_valf() : d2;    // no-op for min
        pm[s]   = fmaxf(pm[s], selP);
        nm[s]   = fminf(nm[s], selN);
        cmP[nj] = fmaxf(cmP[nj], selP);
        cmN[nj] = fminf(cmN[nj], selN);
      }
    }
  }

  // row-side halving butterfly across 16 lanes of each quad group
#pragma unroll
  for (int m = 8; m >= 1; m >>= 1) {
#pragma unroll
    for (int j = 0; j < m; ++j) {
      bool up = (l15 & m) != 0;
      float sp = up ? pm[j] : pm[j + m];
      float sn = up ? nm[j] : nm[j + m];
      float rp = __shfl_xor(sp, m);
      float rn = __shfl_xor(sn, m);
      float kp = up ? pm[j + m] : pm[j];
      float kn = up ? nm[j + m] : nm[j];
      pm[j] = fmaxf(kp, rp);
      nm[j] = fminf(kn, rn);
    }
  }
  {
    int rowIdx = wy * 64 + ((l15 >> 2) << 4) + (quad << 2) + (l15 & 3);
    atomicMax(&pmL[rowIdx], __float_as_uint(pm[0]));
    atomicMin(&nmL[rowIdx], __float_as_uint(nm[0]));
  }

  // col-side: reduce across quads
#pragma unroll
  for (int nj = 0; nj < 4; ++nj) {
    cmP[nj] = fmaxf(cmP[nj], __shfl_xor(cmP[nj], 16));
    cmP[nj] = fmaxf(cmP[nj], __shfl_xor(cmP[nj], 32));
    cmN[nj] = fminf(cmN[nj], __shfl_xor(cmN[nj], 16));
    cmN[nj] = fminf(cmN[nj], __shfl_xor(cmN[nj], 32));
  }
  {
    float vP = (quad == 0) ? cmP[0] : (quad == 1) ? cmP[1] : (quad == 2) ? cmP[2] : cmP[3];
    float vN = (quad == 0) ? cmN[0] : (quad == 1) ? cmN[1] : (quad == 2) ? cmN[2] : cmN[3];
    int colIdx = wx * 64 + quad * 16 + l15;
    atomicMax(&pmLc[colIdx], __float_as_uint(vP));
    atomicMin(&nmLc[colIdx], __float_as_uint(vN));
  }
  __syncthreads();

  if (t < 128) {
    atomicMax(&pmax[rowBase + t], pmL[t]);
    atomicMin(&nmin[rowBase + t], nmL[t]);
  } else {
    int u = t - 128;
    atomicMax(&pmax[colBase + u], pmLc[u]);
    atomicMin(&nmin[colBase + u], nmLc[u]);
  }
}

// ---------------- Kernel C: final loss/prec (1 block) ------------------------
__global__ __launch_bounds__(256) void finish_kernel(
    const unsigned* __restrict__ pmax, const unsigned* __restrict__ nmin,
    float* __restrict__ out) {
  const int t = threadIdx.x;
  float lsum = 0.f, psum = 0.f;
  for (int i = t; i < N; i += 256) {
    float ap = sqrtf(__uint_as_float(pmax[i]));
    float an = sqrtf(__uint_as_float(nmin[i]));
    lsum += fmaxf(ap - an + MARGIN, 0.f);
    psum += (an > ap) ? 1.f : 0.f;
  }
#pragma unroll
  for (int o = 32; o > 0; o >>= 1) {
    lsum += __shfl_down(lsum, o);
    psum += __shfl_down(psum, o);
  }
  __shared__ float ls[4], ps[4];
  if ((t & 63) == 0) { ls[t >> 6] = lsum; ps[t >> 6] = psum; }
  __syncthreads();
  if (t == 0) {
    out[0] = (ls[0] + ls[1] + ls[2] + ls[3]) * (1.0f / (float)N);
    out[1] = (ps[0] + ps[1] + ps[2] + ps[3]) * (1.0f / (float)N);
  }
}

extern "C" void kernel_launch(void* const* d_in, const int* in_sizes, int n_in,
                              void* d_out, int out_size, void* d_ws, size_t ws_size,
                              hipStream_t stream) {
  const float* X  = (const float*)d_in[0];
  const int* tgt  = (const int*)d_in[1];
  float* out      = (float*)d_out;

  char* ws = (char*)d_ws;
  unsigned short* Xb = (unsigned short*)ws;                    // 4 MiB
  float*    sq    = (float*)(ws + 4194304);                    // 32 KiB
  unsigned* pmax  = (unsigned*)(ws + 4194304 + 32768);         // 32 KiB
  unsigned* nmin  = (unsigned*)(ws + 4194304 + 65536);         // 32 KiB

  prep_kernel<<<1024, 256, 0, stream>>>(X, Xb, sq, pmax, nmin);
  tile_kernel<<<NBLK, 256, 0, stream>>>(Xb, sq, tgt, pmax, nmin);
  finish_kernel<<<1, 256, 0, stream>>>(pmax, nmin, out);
}

// Round 2
// 119.988 us; speedup vs baseline: 1.2918x; 1.2918x over previous
//
#include <hip/hip_runtime.h>
#include <hip/hip_bf16.h>

// TripletLoss, N=8192, D=256 fp32, targets in [0,128).
// out[0] = mean(relu(dist_ap - dist_an + 0.3)), out[1] = mean(dist_an > dist_ap)
// dist = sqrt(clip(sq_i + sq_j - 2 dot, 1e-12)); sqrt deferred (monotone);
// d2 > 0 so uint-bit order == float order -> atomicMax/Min on unsigned.
//
// R7: counted-vmcnt pipeline (T3+T4) on the R5 LDS-staged structure.
//  - R6 post-mortem: reg-direct loads (no barriers) were SLOWER (90us) ->
//    latency-bound, not barrier-bound per se; keep coalesced DMA + LDS sharing.
//  - 3 LDS buffers, depth-2 prefetch: phase k issues DMA k+2, waits
//    vmcnt(8/4/0) (own phase-k loads only), raw s_barrier. Loads stay in
//    flight across barriers instead of vmcnt(0)-draining every phase.
//  - Full bank swizzle chunk = quad ^ ((row + row>>2) & 3): R5's
//    quad^(row&3) left lanes {0,4,8,12} on the same bank-quad (4-way
//    conflict, 2.16M conflict cycles). New mapping covers 32 banks 2x (free).
//  - T5 setprio around MFMA; T1 XCD swizzle (2080 %% 8 == 0, bijective).
//  - LDS 52KB -> 3 blocks/CU resident.

#define N 8192
#define D 256
#define MARGIN 0.3f
#define NBLK 2080  // 64*65/2 lower-triangle 128x128 tiles

typedef __bf16  bf16x8  __attribute__((ext_vector_type(8)));
typedef float   floatx4 __attribute__((ext_vector_type(4)));

__device__ __forceinline__ void load_lds16(const void* g, void* s) {
  __builtin_amdgcn_global_load_lds(
      (const __attribute__((address_space(1))) void*)g,
      (__attribute__((address_space(3))) void*)s, 16, 0, 0);
}

// ---------------- Kernel A: bf16 cast + row sq-norms + init ------------------
__global__ __launch_bounds__(256) void prep_kernel(
    const float* __restrict__ X, unsigned short* __restrict__ Xb,
    float* __restrict__ sq, unsigned* __restrict__ pmax, unsigned* __restrict__ nmin) {
  const int t = threadIdx.x;
  const int lane = t & 63, wave = t >> 6;
  const int row0 = blockIdx.x * 8 + wave * 2;
#pragma unroll
  for (int r = 0; r < 2; ++r) {
    const int row = row0 + r;
    float4 v = *reinterpret_cast<const float4*>(X + (size_t)row * D + lane * 4);
    ushort4 h;
    {
      __hip_bfloat16 b0 = __float2bfloat16(v.x), b1 = __float2bfloat16(v.y);
      __hip_bfloat16 b2 = __float2bfloat16(v.z), b3 = __float2bfloat16(v.w);
      h.x = *reinterpret_cast<unsigned short*>(&b0);
      h.y = *reinterpret_cast<unsigned short*>(&b1);
      h.z = *reinterpret_cast<unsigned short*>(&b2);
      h.w = *reinterpret_cast<unsigned short*>(&b3);
    }
    *reinterpret_cast<ushort4*>(Xb + (size_t)row * D + lane * 4) = h;
    float s = v.x * v.x + v.y * v.y + v.z * v.z + v.w * v.w;
#pragma unroll
    for (int o = 32; o > 0; o >>= 1) s += __shfl_down(s, o);
    if (lane == 0) {
      sq[row] = s;
      pmax[row] = 0u;
      nmin[row] = 0x7F800000u;  // +inf
    }
  }
}

// ---------------- Kernel B: triangular tiles, counted-vmcnt pipeline ---------
__global__ __launch_bounds__(256) void tile_kernel(
    const unsigned short* __restrict__ Xb, const float* __restrict__ sq,
    const int* __restrict__ tgt, unsigned* __restrict__ pmax, unsigned* __restrict__ nmin) {
  // T1: XCD-aware swizzle; NBLK % 8 == 0 so the simple form is bijective.
  // Consecutive logical tiles share row/col panels -> per-XCD L2 locality.
  const int hw = blockIdx.x;
  const int bi = (hw & 7) * (NBLK / 8) + (hw >> 3);

  // lower-triangle decode: bi -> (by >= bx)
  int by = (int)((sqrtf(8.0f * (float)bi + 1.0f) - 1.0f) * 0.5f);
  while ((by + 1) * (by + 2) / 2 <= bi) ++by;
  while (by * (by + 1) / 2 > bi) --by;
  const int bx = bi - by * (by + 1) / 2;
  const int rowBase = by * 128, colBase = bx * 128;

  const int t = threadIdx.x;
  const int lane = t & 63, wave = t >> 6;
  const int wy = wave >> 1, wx = wave & 1;
  const int quad = lane >> 4, l15 = lane & 15;

  // 3-deep rotating tile buffers (8 KB each side per phase)
  __shared__ __align__(16) unsigned short As[3][128 * 32];  // 24 KB
  __shared__ __align__(16) unsigned short Bs[3][128 * 32];  // 24 KB
  __shared__ float sqr[128], sqc[128];
  __shared__ int   tr[128], tc[128];
  __shared__ unsigned pmL[128], nmL[128], pmLc[128], nmLc[128];

  if (t < 128) {
    sqr[t] = sq[rowBase + t]; tr[t] = tgt[rowBase + t];
    pmL[t] = 0u; nmL[t] = 0x7F800000u;
  } else {
    int u = t - 128;
    sqc[u] = sq[colBase + u]; tc[u] = tgt[colBase + u];
    pmLc[u] = 0u; nmLc[u] = 0x7F800000u;
  }

  const unsigned short* Ag = Xb + (size_t)rowBase * D;
  const unsigned short* Bg = Xb + (size_t)colBase * D;

  // DMA source pre-swizzle (rule #21: swizzle BOTH sides). LDS chunk slot
  // s of row holds global chunk s ^ f(row), f(row) = (row + (row>>2)) & 3.
  int goff[2], lbase[2];
#pragma unroll
  for (int it = 0; it < 2; ++it) {
    int p = t + it * 256;
    int row = p >> 2;
    int c = (p & 3) ^ ((row + (row >> 2)) & 3);
    goff[it] = row * D + c * 8;
    lbase[it] = (it * 256 + wave * 64) * 16;
  }
  // Swizzled read addresses: each 16-lane group covers all 32 banks exactly
  // 2x (free) -- R5's quad^(row&3) left a 4-way conflict (2.16M cycles).
  int aAddr[4], bAddr[4];
#pragma unroll
  for (int mi = 0; mi < 4; ++mi) {
    int row = wy * 64 + mi * 16 + l15;
    aAddr[mi] = (row * 4 + (quad ^ ((row + (row >> 2)) & 3))) * 16;
  }
#pragma unroll
  for (int nj = 0; nj < 4; ++nj) {
    int col = wx * 64 + nj * 16 + l15;
    bAddr[nj] = (col * 4 + (quad ^ ((col + (col >> 2)) & 3))) * 16;
  }

  floatx4 acc[4][4];
#pragma unroll
  for (int mi = 0; mi < 4; ++mi)
#pragma unroll
    for (int nj = 0; nj < 4; ++nj)
      acc[mi][nj] = (floatx4){0.f, 0.f, 0.f, 0.f};

#define ISSUE_DMA(ph) do {                                                   \
    const int ko_ = (ph) * 32;                                               \
    char* an_ = (char*)As[(ph) % 3];                                         \
    char* bn_ = (char*)Bs[(ph) % 3];                                         \
    _Pragma("unroll")                                                        \
    for (int it = 0; it < 2; ++it) {                                         \
      load_lds16(Ag + goff[it] + ko_, an_ + lbase[it]);                      \
      load_lds16(Bg + goff[it] + ko_, bn_ + lbase[it]);                      \
    }                                                                        \
  } while (0)

  // Per-phase: issue DMA k+2 (overwrites buf (k-1)%3 -- safe: all waves
  // passed the previous phase's post-read barrier with lgkmcnt(0)-secured
  // registers), wait ONLY phase k's own 4 loads (vmcnt counts per-wave,
  // in-order), barrier for cross-wave LDS visibility, read, secure, barrier,
  // MFMA under setprio(1) (T5: 3 resident blocks at different phases).
#define PHASE(kk, VM) do {                                                   \
    if ((kk) < 6) ISSUE_DMA((kk) + 2);                                       \
    asm volatile("s_waitcnt vmcnt(" #VM ")" ::: "memory");                   \
    __builtin_amdgcn_s_barrier();                                            \
    __builtin_amdgcn_sched_barrier(0);                                       \
    const char* ab_ = (const char*)As[(kk) % 3];                             \
    const char* bb_ = (const char*)Bs[(kk) % 3];                             \
    bf16x8 a_[4], b_[4];                                                     \
    _Pragma("unroll")                                                        \
    for (int mi = 0; mi < 4; ++mi)                                           \
      a_[mi] = *reinterpret_cast<const bf16x8*>(ab_ + aAddr[mi]);            \
    _Pragma("unroll")                                                        \
    for (int nj = 0; nj < 4; ++nj)                                           \
      b_[nj] = *reinterpret_cast<const bf16x8*>(bb_ + bAddr[nj]);            \
    asm volatile("s_waitcnt lgkmcnt(0)" ::: "memory");                       \
    __builtin_amdgcn_sched_barrier(0);                                       \
    __builtin_amdgcn_s_barrier();                                            \
    __builtin_amdgcn_sched_barrier(0);                                       \
    __builtin_amdgcn_s_setprio(1);                                           \
    _Pragma("unroll")                                                        \
    for (int mi = 0; mi < 4; ++mi)                                           \
      _Pragma("unroll")                                                      \
      for (int nj = 0; nj < 4; ++nj)                                         \
        acc[mi][nj] = __builtin_amdgcn_mfma_f32_16x16x32_bf16(               \
            a_[mi], b_[nj], acc[mi][nj], 0, 0, 0);                           \
    __builtin_amdgcn_s_setprio(0);                                           \
    __builtin_amdgcn_sched_barrier(0);                                       \
  } while (0)

  // prologue: phases 0 and 1 in flight (8 loads/thread outstanding)
  ISSUE_DMA(0);
  ISSUE_DMA(1);

  PHASE(0, 8);
  PHASE(1, 8);
  PHASE(2, 8);
  PHASE(3, 8);
  PHASE(4, 8);
  PHASE(5, 8);
  PHASE(6, 4);
  PHASE(7, 0);

#undef PHASE
#undef ISSUE_DMA

  __syncthreads();  // sqr/sqc/tr/tc + pmL/nmL inits fully visible

  // ---- two-sided epilogue on clipped d2 ----
  float sqc_l[4]; int tc_l[4];
#pragma unroll
  for (int nj = 0; nj < 4; ++nj) {
    int jl = wx * 64 + nj * 16 + l15;
    sqc_l[nj] = sqc[jl];
    tc_l[nj]  = tc[jl];
  }

  float pm[16], nm[16], cmP[4], cmN[4];
#pragma unroll
  for (int s = 0; s < 16; ++s) { pm[s] = 0.f; nm[s] = __builtin_huge_valf(); }
#pragma unroll
  for (int nj = 0; nj < 4; ++nj) { cmP[nj] = 0.f; cmN[nj] = __builtin_huge_valf(); }

#pragma unroll
  for (int mi = 0; mi < 4; ++mi) {
#pragma unroll
    for (int r = 0; r < 4; ++r) {
      int il = wy * 64 + mi * 16 + quad * 4 + r;
      float si = sqr[il];
      int   ti = tr[il];
      int   s  = mi * 4 + r;
#pragma unroll
      for (int nj = 0; nj < 4; ++nj) {
        float d2 = fmaxf(fmaf(-2.f, acc[mi][nj][r], si + sqc_l[nj]), 1e-12f);
        bool same = (ti == tc_l[nj]);
        float selP = same ? d2 : 0.f;                      // no-op for max
        float selN = same ? __builtin_huge_valf() : d2;    // no-op for min
        pm[s]   = fmaxf(pm[s], selP);
        nm[s]   = fminf(nm[s], selN);
        cmP[nj] = fmaxf(cmP[nj], selP);
        cmN[nj] = fminf(cmN[nj], selN);
      }
    }
  }

  // row-side halving butterfly across 16 lanes of each quad group
#pragma unroll
  for (int m = 8; m >= 1; m >>= 1) {
#pragma unroll
    for (int j = 0; j < m; ++j) {
      bool up = (l15 & m) != 0;
      float sp = up ? pm[j] : pm[j + m];
      float sn = up ? nm[j] : nm[j + m];
      float rp = __shfl_xor(sp, m);
      float rn = __shfl_xor(sn, m);
      float kp = up ? pm[j + m] : pm[j];
      float kn = up ? nm[j + m] : nm[j];
      pm[j] = fmaxf(kp, rp);
      nm[j] = fminf(kn, rn);
    }
  }
  {
    int rowIdx = wy * 64 + ((l15 >> 2) << 4) + (quad << 2) + (l15 & 3);
    atomicMax(&pmL[rowIdx], __float_as_uint(pm[0]));
    atomicMin(&nmL[rowIdx], __float_as_uint(nm[0]));
  }

  // col-side: reduce across quads
#pragma unroll
  for (int nj = 0; nj < 4; ++nj) {
    cmP[nj] = fmaxf(cmP[nj], __shfl_xor(cmP[nj], 16));
    cmP[nj] = fmaxf(cmP[nj], __shfl_xor(cmP[nj], 32));
    cmN[nj] = fminf(cmN[nj], __shfl_xor(cmN[nj], 16));
    cmN[nj] = fminf(cmN[nj], __shfl_xor(cmN[nj], 32));
  }
  {
    float vP = (quad == 0) ? cmP[0] : (quad == 1) ? cmP[1] : (quad == 2) ? cmP[2] : cmP[3];
    float vN = (quad == 0) ? cmN[0] : (quad == 1) ? cmN[1] : (quad == 2) ? cmN[2] : cmN[3];
    int colIdx = wx * 64 + quad * 16 + l15;
    atomicMax(&pmLc[colIdx], __float_as_uint(vP));
    atomicMin(&nmLc[colIdx], __float_as_uint(vN));
  }
  __syncthreads();

  if (t < 128) {
    atomicMax(&pmax[rowBase + t], pmL[t]);
    atomicMin(&nmin[rowBase + t], nmL[t]);
  } else {
    int u = t - 128;
    atomicMax(&pmax[colBase + u], pmLc[u]);
    atomicMin(&nmin[colBase + u], nmLc[u]);
  }
}

// ---------------- Kernel C: final loss/prec (1 block) ------------------------
__global__ __launch_bounds__(256) void finish_kernel(
    const unsigned* __restrict__ pmax, const unsigned* __restrict__ nmin,
    float* __restrict__ out) {
  const int t = threadIdx.x;
  float lsum = 0.f, psum = 0.f;
  for (int i = t; i < N; i += 256) {
    float ap = sqrtf(__uint_as_float(pmax[i]));
    float an = sqrtf(__uint_as_float(nmin[i]));
    lsum += fmaxf(ap - an + MARGIN, 0.f);
    psum += (an > ap) ? 1.f : 0.f;
  }
#pragma unroll
  for (int o = 32; o > 0; o >>= 1) {
    lsum += __shfl_down(lsum, o);
    psum += __shfl_down(psum, o);
  }
  __shared__ float ls[4], ps[4];
  if ((t & 63) == 0) { ls[t >> 6] = lsum; ps[t >> 6] = psum; }
  __syncthreads();
  if (t == 0) {
    out[0] = (ls[0] + ls[1] + ls[2] + ls[3]) * (1.0f / (float)N);
    out[1] = (ps[0] + ps[1] + ps[2] + ps[3]) * (1.0f / (float)N);
  }
}

extern "C" void kernel_launch(void* const* d_in, const int* in_sizes, int n_in,
                              void* d_out, int out_size, void* d_ws, size_t ws_size,
                              hipStream_t stream) {
  const float* X  = (const float*)d_in[0];
  const int* tgt  = (const int*)d_in[1];
  float* out      = (float*)d_out;

  char* ws = (char*)d_ws;
  unsigned short* Xb = (unsigned short*)ws;                    // 4 MiB
  float*    sq    = (float*)(ws + 4194304);                    // 32 KiB
  unsigned* pmax  = (unsigned*)(ws + 4194304 + 32768);         // 32 KiB
  unsigned* nmin  = (unsigned*)(ws + 4194304 + 65536);         // 32 KiB

  prep_kernel<<<1024, 256, 0, stream>>>(X, Xb, sq, pmax, nmin);
  tile_kernel<<<NBLK, 256, 0, stream>>>(Xb, sq, tgt, pmax, nmin);
  finish_kernel<<<1, 256, 0, stream>>>(pmax, nmin, out);
}

// Round 3
// 113.763 us; speedup vs baseline: 1.3625x; 1.0547x over previous
//
#include <hip/hip_runtime.h>
#include <hip/hip_bf16.h>

// TripletLoss, N=8192, D=256 fp32, targets in [0,128).
// out[0] = mean(relu(dist_ap - dist_an + 0.3)), out[1] = mean(dist_an > dist_ap)
// dist = sqrt(clip(sq_i + sq_j - 2 dot, 1e-12)); sqrt deferred (monotone);
// d2 > 0 so uint-bit order == float order -> atomicMax/Min on unsigned.
//
// R8 (from R7's counted-vmcnt pipeline, tile 52us profiled):
//  - SINGLE barrier per phase (8 vs 16): with 3-deep buffers, moving the
//    per-wave vmcnt(own phase-k loads) BEFORE s_barrier gives cross-wave LDS
//    validity at barrier-exit; DMA k+2 issued post-barrier overwrites buf
//    (k-1)%3 whose reads every wave secured (lgkmcnt(0) pre-MFMA) before
//    arriving. Wait ladder: vmcnt(4) x7, vmcnt(0) x1.
//  - FUSED finish: pmax/nmin are touched ONLY by device-scope atomics (no
//    dirty L2 lines -> no threadfence/wbl2 needed, unlike R3/R4). Epilogue
//    atomic returns captured + vmcnt(0), then relaxed atomicAdd on arrival
//    counter; last block re-reads via __hip_atomic_load(AGENT) (coherent,
//    pipelined plain loads) and writes out[] inline. One dispatch + gap saved.
//  - SQ_LDS_BANK_CONFLICT ~2.16M is the global_load_lds DMA-write path
//    (invariant to read swizzle; R5 vs R7 bit-identical) - not actionable.

#define N 8192
#define D 256
#define MARGIN 0.3f
#define NBLK 2080  // 64*65/2 lower-triangle 128x128 tiles

typedef __bf16  bf16x8  __attribute__((ext_vector_type(8)));
typedef float   floatx4 __attribute__((ext_vector_type(4)));

__device__ __forceinline__ void load_lds16(const void* g, void* s) {
  __builtin_amdgcn_global_load_lds(
      (const __attribute__((address_space(1))) void*)g,
      (__attribute__((address_space(3))) void*)s, 16, 0, 0);
}

// ---------------- Kernel A: bf16 cast + row sq-norms + init ------------------
__global__ __launch_bounds__(256) void prep_kernel(
    const float* __restrict__ X, unsigned short* __restrict__ Xb,
    float* __restrict__ sq, unsigned* __restrict__ pmax, unsigned* __restrict__ nmin,
    unsigned* __restrict__ cnt) {
  const int t = threadIdx.x;
  if (blockIdx.x == 0 && t == 0) *cnt = 0u;  // re-poison arrival counter
  const int lane = t & 63, wave = t >> 6;
  const int row0 = blockIdx.x * 8 + wave * 2;
#pragma unroll
  for (int r = 0; r < 2; ++r) {
    const int row = row0 + r;
    float4 v = *reinterpret_cast<const float4*>(X + (size_t)row * D + lane * 4);
    ushort4 h;
    {
      __hip_bfloat16 b0 = __float2bfloat16(v.x), b1 = __float2bfloat16(v.y);
      __hip_bfloat16 b2 = __float2bfloat16(v.z), b3 = __float2bfloat16(v.w);
      h.x = *reinterpret_cast<unsigned short*>(&b0);
      h.y = *reinterpret_cast<unsigned short*>(&b1);
      h.z = *reinterpret_cast<unsigned short*>(&b2);
      h.w = *reinterpret_cast<unsigned short*>(&b3);
    }
    *reinterpret_cast<ushort4*>(Xb + (size_t)row * D + lane * 4) = h;
    float s = v.x * v.x + v.y * v.y + v.z * v.z + v.w * v.w;
#pragma unroll
    for (int o = 32; o > 0; o >>= 1) s += __shfl_down(s, o);
    if (lane == 0) {
      sq[row] = s;
      pmax[row] = 0u;
      nmin[row] = 0x7F800000u;  // +inf
    }
  }
}

// ---------------- Kernel B: triangular tiles + fused finish ------------------
__global__ __launch_bounds__(256) void tile_kernel(
    const unsigned short* __restrict__ Xb, const float* __restrict__ sq,
    const int* __restrict__ tgt, unsigned* __restrict__ pmax,
    unsigned* __restrict__ nmin, unsigned* __restrict__ cnt,
    float* __restrict__ out) {
  // T1: XCD-aware swizzle; NBLK % 8 == 0 so the simple form is bijective.
  const int hw = blockIdx.x;
  const int bi = (hw & 7) * (NBLK / 8) + (hw >> 3);

  // lower-triangle decode: bi -> (by >= bx)
  int by = (int)((sqrtf(8.0f * (float)bi + 1.0f) - 1.0f) * 0.5f);
  while ((by + 1) * (by + 2) / 2 <= bi) ++by;
  while (by * (by + 1) / 2 > bi) --by;
  const int bx = bi - by * (by + 1) / 2;
  const int rowBase = by * 128, colBase = bx * 128;

  const int t = threadIdx.x;
  const int lane = t & 63, wave = t >> 6;
  const int wy = wave >> 1, wx = wave & 1;
  const int quad = lane >> 4, l15 = lane & 15;

  // 3-deep rotating tile buffers (8 KB each side per phase)
  __shared__ __align__(16) unsigned short As[3][128 * 32];  // 24 KB
  __shared__ __align__(16) unsigned short Bs[3][128 * 32];  // 24 KB
  __shared__ float sqr[128], sqc[128];
  __shared__ int   tr[128], tc[128];
  __shared__ unsigned pmL[128], nmL[128], pmLc[128], nmLc[128];
  __shared__ unsigned lastFlag;
  __shared__ float fls[4], fps[4];

  if (t < 128) {
    sqr[t] = sq[rowBase + t]; tr[t] = tgt[rowBase + t];
    pmL[t] = 0u; nmL[t] = 0x7F800000u;
  } else {
    int u = t - 128;
    sqc[u] = sq[colBase + u]; tc[u] = tgt[colBase + u];
    pmLc[u] = 0u; nmLc[u] = 0x7F800000u;
  }

  const unsigned short* Ag = Xb + (size_t)rowBase * D;
  const unsigned short* Bg = Xb + (size_t)colBase * D;

  // DMA source pre-swizzle (both sides or neither). LDS chunk slot s of row
  // holds global chunk s ^ f(row), f(row) = (row + (row>>2)) & 3.
  int goff[2], lbase[2];
#pragma unroll
  for (int it = 0; it < 2; ++it) {
    int p = t + it * 256;
    int row = p >> 2;
    int c = (p & 3) ^ ((row + (row >> 2)) & 3);
    goff[it] = row * D + c * 8;
    lbase[it] = (it * 256 + wave * 64) * 16;
  }
  int aAddr[4], bAddr[4];
#pragma unroll
  for (int mi = 0; mi < 4; ++mi) {
    int row = wy * 64 + mi * 16 + l15;
    aAddr[mi] = (row * 4 + (quad ^ ((row + (row >> 2)) & 3))) * 16;
  }
#pragma unroll
  for (int nj = 0; nj < 4; ++nj) {
    int col = wx * 64 + nj * 16 + l15;
    bAddr[nj] = (col * 4 + (quad ^ ((col + (col >> 2)) & 3))) * 16;
  }

  floatx4 acc[4][4];
#pragma unroll
  for (int mi = 0; mi < 4; ++mi)
#pragma unroll
    for (int nj = 0; nj < 4; ++nj)
      acc[mi][nj] = (floatx4){0.f, 0.f, 0.f, 0.f};

#define ISSUE_DMA(ph) do {                                                   \
    const int ko_ = (ph) * 32;                                               \
    char* an_ = (char*)As[(ph) % 3];                                         \
    char* bn_ = (char*)Bs[(ph) % 3];                                         \
    _Pragma("unroll")                                                        \
    for (int it = 0; it < 2; ++it) {                                         \
      load_lds16(Ag + goff[it] + ko_, an_ + lbase[it]);                      \
      load_lds16(Bg + goff[it] + ko_, bn_ + lbase[it]);                      \
    }                                                                        \
  } while (0)

  // Single barrier per phase. Correctness ledger:
  //  * vmcnt(VM) BEFORE barrier: each wave drains its OWN phase-k DMA group
  //    (groups are 4 loads; allow only the newer group k+1 -> VM=4; tail
  //    VM=0). All waves drained before any exits the barrier => whole tile
  //    k%3 valid cross-wave at barrier-exit.
  //  * ISSUE k+2 AFTER barrier: writes buf (k+2)%3 == (k-1)%3. Every wave
  //    secured its phase-(k-1) ds_reads into registers (lgkmcnt(0) before
  //    its MFMA k-1) before arriving at this barrier -> WAR safe.
#define PHASE(kk, VM) do {                                                   \
    asm volatile("s_waitcnt vmcnt(" #VM ")" ::: "memory");                   \
    __builtin_amdgcn_s_barrier();                                            \
    __builtin_amdgcn_sched_barrier(0);                                       \
    const char* ab_ = (const char*)As[(kk) % 3];                             \
    const char* bb_ = (const char*)Bs[(kk) % 3];                             \
    bf16x8 a_[4], b_[4];                                                     \
    _Pragma("unroll")                                                        \
    for (int mi = 0; mi < 4; ++mi)                                           \
      a_[mi] = *reinterpret_cast<const bf16x8*>(ab_ + aAddr[mi]);            \
    _Pragma("unroll")                                                        \
    for (int nj = 0; nj < 4; ++nj)                                           \
      b_[nj] = *reinterpret_cast<const bf16x8*>(bb_ + bAddr[nj]);            \
    if ((kk) < 6) ISSUE_DMA((kk) + 2);                                       \
    asm volatile("s_waitcnt lgkmcnt(0)" ::: "memory");                       \
    __builtin_amdgcn_sched_barrier(0);                                       \
    __builtin_amdgcn_s_setprio(1);                                           \
    _Pragma("unroll")                                                        \
    for (int mi = 0; mi < 4; ++mi)                                           \
      _Pragma("unroll")                                                      \
      for (int nj = 0; nj < 4; ++nj)                                         \
        acc[mi][nj] = __builtin_amdgcn_mfma_f32_16x16x32_bf16(               \
            a_[mi], b_[nj], acc[mi][nj], 0, 0, 0);                           \
    __builtin_amdgcn_s_setprio(0);                                           \
    __builtin_amdgcn_sched_barrier(0);                                       \
  } while (0)

  // prologue: phases 0 and 1 in flight
  ISSUE_DMA(0);
  ISSUE_DMA(1);

  PHASE(0, 4);
  PHASE(1, 4);
  PHASE(2, 4);
  PHASE(3, 4);
  PHASE(4, 4);
  PHASE(5, 4);
  PHASE(6, 4);
  PHASE(7, 0);

#undef PHASE
#undef ISSUE_DMA

  __syncthreads();

  // ---- two-sided epilogue on clipped d2 ----
  float sqc_l[4]; int tc_l[4];
#pragma unroll
  for (int nj = 0; nj < 4; ++nj) {
    int jl = wx * 64 + nj * 16 + l15;
    sqc_l[nj] = sqc[jl];
    tc_l[nj]  = tc[jl];
  }

  float pm[16], nm[16], cmP[4], cmN[4];
#pragma unroll
  for (int s = 0; s < 16; ++s) { pm[s] = 0.f; nm[s] = __builtin_huge_valf(); }
#pragma unroll
  for (int nj = 0; nj < 4; ++nj) { cmP[nj] = 0.f; cmN[nj] = __builtin_huge_valf(); }

#pragma unroll
  for (int mi = 0; mi < 4; ++mi) {
#pragma unroll
    for (int r = 0; r < 4; ++r) {
      int il = wy * 64 + mi * 16 + quad * 4 + r;
      float si = sqr[il];
      int   ti = tr[il];
      int   s  = mi * 4 + r;
#pragma unroll
      for (int nj = 0; nj < 4; ++nj) {
        float d2 = fmaxf(fmaf(-2.f, acc[mi][nj][r], si + sqc_l[nj]), 1e-12f);
        bool same = (ti == tc_l[nj]);
        float selP = same ? d2 : 0.f;                      // no-op for max
        float selN = same ? __builtin_huge_valf() : d2;    // no-op for min
        pm[s]   = fmaxf(pm[s], selP);
        nm[s]   = fminf(nm[s], selN);
        cmP[nj] = fmaxf(cmP[nj], selP);
        cmN[nj] = fminf(cmN[nj], selN);
      }
    }
  }

  // row-side halving butterfly across 16 lanes of each quad group
#pragma unroll
  for (int m = 8; m >= 1; m >>= 1) {
#pragma unroll
    for (int j = 0; j < m; ++j) {
      bool up = (l15 & m) != 0;
      float sp = up ? pm[j] : pm[j + m];
      float sn = up ? nm[j] : nm[j + m];
      float rp = __shfl_xor(sp, m);
      float rn = __shfl_xor(sn, m);
      float kp = up ? pm[j + m] : pm[j];
      float kn = up ? nm[j + m] : nm[j];
      pm[j] = fmaxf(kp, rp);
      nm[j] = fminf(kn, rn);
    }
  }
  {
    int rowIdx = wy * 64 + ((l15 >> 2) << 4) + (quad << 2) + (l15 & 3);
    atomicMax(&pmL[rowIdx], __float_as_uint(pm[0]));
    atomicMin(&nmL[rowIdx], __float_as_uint(nm[0]));
  }

  // col-side: reduce across quads
#pragma unroll
  for (int nj = 0; nj < 4; ++nj) {
    cmP[nj] = fmaxf(cmP[nj], __shfl_xor(cmP[nj], 16));
    cmP[nj] = fmaxf(cmP[nj], __shfl_xor(cmP[nj], 32));
    cmN[nj] = fminf(cmN[nj], __shfl_xor(cmN[nj], 16));
    cmN[nj] = fminf(cmN[nj], __shfl_xor(cmN[nj], 32));
  }
  {
    float vP = (quad == 0) ? cmP[0] : (quad == 1) ? cmP[1] : (quad == 2) ? cmP[2] : cmP[3];
    float vN = (quad == 0) ? cmN[0] : (quad == 1) ? cmN[1] : (quad == 2) ? cmN[2] : cmN[3];
    int colIdx = wx * 64 + quad * 16 + l15;
    atomicMax(&pmLc[colIdx], __float_as_uint(vP));
    atomicMin(&nmLc[colIdx], __float_as_uint(vN));
  }
  __syncthreads();

  // Global atomics with captured returns (forces sc0; completion = RMW done
  // at the device-coherent point once vmcnt(0) drains).
  unsigned keep;
  if (t < 128) {
    unsigned o1 = atomicMax(&pmax[rowBase + t], pmL[t]);
    unsigned o2 = atomicMin(&nmin[rowBase + t], nmL[t]);
    keep = o1 ^ o2;
  } else {
    int u = t - 128;
    unsigned o1 = atomicMax(&pmax[colBase + u], pmLc[u]);
    unsigned o2 = atomicMin(&nmin[colBase + u], nmLc[u]);
    keep = o1 ^ o2;
  }
  asm volatile("" :: "v"(keep));  // keep returns live (no DCE of sc0)
  asm volatile("s_waitcnt vmcnt(0)" ::: "memory");
  __syncthreads();

  // arrival counter: all this block's RMWs are committed at the coherent
  // point (returns drained above); no L2-dirty plain stores exist, so no
  // release fence (buffer_wbl2) is needed -- the R3/R4 trap.
  if (t == 0) lastFlag = (atomicAdd(cnt, 1u) == NBLK - 1u) ? 1u : 0u;
  __syncthreads();

  if (lastFlag) {
    // ---- fused finish: coherent (agent-scope) loads, fully pipelined ----
    float lsum = 0.f, psum = 0.f;
#pragma unroll 4
    for (int i = t; i < N; i += 256) {
      unsigned pu = __hip_atomic_load(&pmax[i], __ATOMIC_RELAXED, __HIP_MEMORY_SCOPE_AGENT);
      unsigned nu = __hip_atomic_load(&nmin[i], __ATOMIC_RELAXED, __HIP_MEMORY_SCOPE_AGENT);
      float ap = sqrtf(__uint_as_float(pu));
      float an = sqrtf(__uint_as_float(nu));
      lsum += fmaxf(ap - an + MARGIN, 0.f);
      psum += (an > ap) ? 1.f : 0.f;
    }
#pragma unroll
    for (int o = 32; o > 0; o >>= 1) {
      lsum += __shfl_down(lsum, o);
      psum += __shfl_down(psum, o);
    }
    if ((t & 63) == 0) { fls[t >> 6] = lsum; fps[t >> 6] = psum; }
    __syncthreads();
    if (t == 0) {
      out[0] = (fls[0] + fls[1] + fls[2] + fls[3]) * (1.0f / (float)N);
      out[1] = (fps[0] + fps[1] + fps[2] + fps[3]) * (1.0f / (float)N);
    }
  }
}

extern "C" void kernel_launch(void* const* d_in, const int* in_sizes, int n_in,
                              void* d_out, int out_size, void* d_ws, size_t ws_size,
                              hipStream_t stream) {
  const float* X  = (const float*)d_in[0];
  const int* tgt  = (const int*)d_in[1];
  float* out      = (float*)d_out;

  char* ws = (char*)d_ws;
  unsigned short* Xb = (unsigned short*)ws;                    // 4 MiB
  float*    sq    = (float*)(ws + 4194304);                    // 32 KiB
  unsigned* pmax  = (unsigned*)(ws + 4194304 + 32768);         // 32 KiB
  unsigned* nmin  = (unsigned*)(ws + 4194304 + 65536);         // 32 KiB
  unsigned* cnt   = (unsigned*)(ws + 4194304 + 98304);         // 4 B

  prep_kernel<<<1024, 256, 0, stream>>>(X, Xb, sq, pmax, nmin, cnt);
  tile_kernel<<<NBLK, 256, 0, stream>>>(Xb, sq, tgt, pmax, nmin, cnt, out);
}

// Round 4
// 105.933 us; speedup vs baseline: 1.4632x; 1.0739x over previous
//
#include <hip/hip_runtime.h>
#include <hip/hip_bf16.h>

// TripletLoss, N=8192, D=256 fp32, targets in [0,128).
// out[0] = mean(relu(dist_ap - dist_an + 0.3)), out[1] = mean(dist_an > dist_ap)
// dist = sqrt(clip(sq_i + sq_j - 2 dot, 1e-12)); sqrt deferred (monotone);
// clipped d2 >= 0 so uint-bit order == float order -> atomicMax/Min unsigned.
//
// R9: amortize per-block fixed costs 2x with 256x128 tiles (was 128x128).
//  - R8 post-mortem: every pipe <25% busy; cost = per-block overheads
//    (decode, DMA warmup, 8 sync events, epilogue, RMWs) x 2080 blocks.
//  - 1056 blocks (256-row x 128-col triangle cover; boundary tiles compute
//    some upper-triangle pairs redundantly -- idempotent for max/min).
//  - 4 waves, wave-tile 64x128: acc[4][8], 32 MFMA + 12 ds_read/phase/wave
//    (2x compute per sync event). VGPR ~200 -> __launch_bounds__(256,2).
//  - LDS 78KB (3-deep A 48K + B 24K + misc) -> 2 blocks/CU; occupancy flat
//    (VGPR-capped at 8 waves/CU anyway) but all per-block costs halved.
//  - Counted-vmcnt depth-2 pipeline, single barrier per phase (R8 ledger).
//  - Epilogue clip deferred out of inner loop; re-applied before every
//    uint-ordered atomic (required: sign trick needs values >= 0).
//  - Fused finish via arrival counter kept (R8, proven).

#define N 8192
#define D 256
#define MARGIN 0.3f
#define NBLK 1056  // sum over by=0..31 of (2*by+2) 256x128 tiles

typedef __bf16  bf16x8  __attribute__((ext_vector_type(8)));
typedef float   floatx4 __attribute__((ext_vector_type(4)));

__device__ __forceinline__ void load_lds16(const void* g, void* s) {
  __builtin_amdgcn_global_load_lds(
      (const __attribute__((address_space(1))) void*)g,
      (__attribute__((address_space(3))) void*)s, 16, 0, 0);
}

// ---------------- Kernel A: bf16 cast + row sq-norms + init ------------------
__global__ __launch_bounds__(256) void prep_kernel(
    const float* __restrict__ X, unsigned short* __restrict__ Xb,
    float* __restrict__ sq, unsigned* __restrict__ pmax, unsigned* __restrict__ nmin,
    unsigned* __restrict__ cnt) {
  const int t = threadIdx.x;
  if (blockIdx.x == 0 && t == 0) *cnt = 0u;  // re-poison arrival counter
  const int lane = t & 63, wave = t >> 6;
  const int row0 = blockIdx.x * 8 + wave * 2;
#pragma unroll
  for (int r = 0; r < 2; ++r) {
    const int row = row0 + r;
    float4 v = *reinterpret_cast<const float4*>(X + (size_t)row * D + lane * 4);
    ushort4 h;
    {
      __hip_bfloat16 b0 = __float2bfloat16(v.x), b1 = __float2bfloat16(v.y);
      __hip_bfloat16 b2 = __float2bfloat16(v.z), b3 = __float2bfloat16(v.w);
      h.x = *reinterpret_cast<unsigned short*>(&b0);
      h.y = *reinterpret_cast<unsigned short*>(&b1);
      h.z = *reinterpret_cast<unsigned short*>(&b2);
      h.w = *reinterpret_cast<unsigned short*>(&b3);
    }
    *reinterpret_cast<ushort4*>(Xb + (size_t)row * D + lane * 4) = h;
    float s = v.x * v.x + v.y * v.y + v.z * v.z + v.w * v.w;
#pragma unroll
    for (int o = 32; o > 0; o >>= 1) s += __shfl_down(s, o);
    if (lane == 0) {
      sq[row] = s;
      pmax[row] = 0u;
      nmin[row] = 0x7F800000u;  // +inf
    }
  }
}

// ---------------- Kernel B: 256x128 triangular tiles + fused finish ----------
__global__ __launch_bounds__(256, 2) void tile_kernel(
    const unsigned short* __restrict__ Xb, const float* __restrict__ sq,
    const int* __restrict__ tgt, unsigned* __restrict__ pmax,
    unsigned* __restrict__ nmin, unsigned* __restrict__ cnt,
    float* __restrict__ out) {
  // T1: XCD-aware swizzle; NBLK % 8 == 0 (1056 = 8*132), bijective.
  const int hw = blockIdx.x;
  const int bi = (hw & 7) * (NBLK / 8) + (hw >> 3);

  // Triangle cover by 256-row x 128-col tiles: tile (by,bx) exists for
  // bx in [0, 2*by+2). Cumulative count C(by) = by*(by+1).
  int by = (int)((sqrtf(4.0f * (float)bi + 1.0f) - 1.0f) * 0.5f);
  while ((by + 1) * (by + 2) <= bi) ++by;
  while (by * (by + 1) > bi) --by;
  const int bx = bi - by * (by + 1);
  const int rowBase = by * 256, colBase = bx * 128;

  const int t = threadIdx.x;
  const int lane = t & 63, wave = t >> 6;
  const int wy = wave;               // wave-tile: rows [wy*64, wy*64+64)
  const int quad = lane >> 4, l15 = lane & 15;

  // 3-deep rotating buffers: A 256x32 (16KB) x3, B 128x32 (8KB) x3
  __shared__ __align__(16) unsigned short As[3][256 * 32];  // 48 KB
  __shared__ __align__(16) unsigned short Bs[3][128 * 32];  // 24 KB
  __shared__ float sqr[256], sqc[128];
  __shared__ int   tr[256], tc[128];
  __shared__ unsigned pmL[256], nmL[256], pmLc[128], nmLc[128];
  __shared__ unsigned lastFlag;
  __shared__ float fls[4], fps[4];

  sqr[t] = sq[rowBase + t]; tr[t] = tgt[rowBase + t];
  pmL[t] = 0u; nmL[t] = 0x7F800000u;
  if (t < 128) {
    sqc[t] = sq[colBase + t]; tc[t] = tgt[colBase + t];
    pmLc[t] = 0u; nmLc[t] = 0x7F800000u;
  }

  const unsigned short* Ag = Xb + (size_t)rowBase * D;
  const unsigned short* Bg = Xb + (size_t)colBase * D;

  // DMA source pre-swizzle (both sides or neither): LDS slot s of row holds
  // global chunk s ^ f(row), f(x) = (x + (x>>2)) & 3. f is invariant under
  // +16/+64 multiples, so one base + immediates covers all subtiles.
  const int r0 = t >> 2;                              // 0..63
  const int cA = (t & 3) ^ ((r0 + (r0 >> 2)) & 3);
  const int g0 = r0 * D + cA * 8;                     // elements
  const int wl = wave * 1024;                         // LDS bytes (slot t*16)

  // ds_read bases (swizzled); per-mi/nj/buffer offsets are immediates.
  const int fq  = (l15 + (l15 >> 2)) & 3;
  const int aA0 = ((wy * 64 + l15) * 4 + (quad ^ fq)) * 16;  // + mi*1024 + buf*16384
  const int bA0 = (l15 * 4 + (quad ^ fq)) * 16;              // + nj*1024 + buf*8192
  const char* AsB = (const char*)As;
  const char* BsB = (const char*)Bs;

  floatx4 acc[4][8];
#pragma unroll
  for (int mi = 0; mi < 4; ++mi)
#pragma unroll
    for (int nj = 0; nj < 8; ++nj)
      acc[mi][nj] = (floatx4){0.f, 0.f, 0.f, 0.f};

  // 6 DMA loads/thread/phase: A rows r0+it*64 (it 0..3), B cols r0+jt*64.
#define ISSUE_DMA(ph) do {                                                   \
    const int ko_ = (ph) * 32;                                               \
    char* an_ = (char*)As[(ph) % 3];                                         \
    char* bn_ = (char*)Bs[(ph) % 3];                                         \
    _Pragma("unroll")                                                        \
    for (int it = 0; it < 4; ++it)                                           \
      load_lds16(Ag + g0 + it * (64 * D) + ko_, an_ + wl + it * 4096);       \
    _Pragma("unroll")                                                        \
    for (int jt = 0; jt < 2; ++jt)                                           \
      load_lds16(Bg + g0 + jt * (64 * D) + ko_, bn_ + wl + jt * 4096);       \
  } while (0)

  // Single barrier per phase (R8 ledger):
  //  * vmcnt(VM) BEFORE barrier drains this wave's phase-k DMA group (6
  //    loads; group k+1 still outstanding -> VM=6; tail VM=0). All waves
  //    drained before any exits => tile k%3 valid cross-wave at exit.
  //  * ISSUE k+2 after the barrier overwrites buf (k-1)%3; every wave
  //    secured its phase-(k-1) ds_reads (lgkmcnt(0)) before arriving.
#define PHASE(kk, VM) do {                                                   \
    asm volatile("s_waitcnt vmcnt(" #VM ")" ::: "memory");                   \
    __builtin_amdgcn_s_barrier();                                            \
    __builtin_amdgcn_sched_barrier(0);                                       \
    const char* ab_ = AsB + ((kk) % 3) * 16384;                              \
    const char* bb_ = BsB + ((kk) % 3) * 8192;                               \
    bf16x8 a_[4], b_[8];                                                     \
    _Pragma("unroll")                                                        \
    for (int mi = 0; mi < 4; ++mi)                                           \
      a_[mi] = *reinterpret_cast<const bf16x8*>(ab_ + aA0 + mi * 1024);      \
    _Pragma("unroll")                                                        \
    for (int nj = 0; nj < 8; ++nj)                                           \
      b_[nj] = *reinterpret_cast<const bf16x8*>(bb_ + bA0 + nj * 1024);      \
    if ((kk) < 6) ISSUE_DMA((kk) + 2);                                       \
    asm volatile("s_waitcnt lgkmcnt(0)" ::: "memory");                       \
    __builtin_amdgcn_sched_barrier(0);                                       \
    __builtin_amdgcn_s_setprio(1);                                           \
    _Pragma("unroll")                                                        \
    for (int mi = 0; mi < 4; ++mi)                                           \
      _Pragma("unroll")                                                      \
      for (int nj = 0; nj < 8; ++nj)                                         \
        acc[mi][nj] = __builtin_amdgcn_mfma_f32_16x16x32_bf16(               \
            a_[mi], b_[nj], acc[mi][nj], 0, 0, 0);                           \
    __builtin_amdgcn_s_setprio(0);                                           \
    __builtin_amdgcn_sched_barrier(0);                                       \
  } while (0)

  // prologue: phases 0 and 1 in flight (12 loads/thread outstanding)
  ISSUE_DMA(0);
  ISSUE_DMA(1);

  PHASE(0, 6);
  PHASE(1, 6);
  PHASE(2, 6);
  PHASE(3, 6);
  PHASE(4, 6);
  PHASE(5, 6);
  PHASE(6, 6);
  PHASE(7, 0);

#undef PHASE
#undef ISSUE_DMA

  __syncthreads();

  // ---- two-sided epilogue on UNclipped d2 (clip deferred to pushes) ----
  float sqc_l[8]; int tc_l[8];
#pragma unroll
  for (int nj = 0; nj < 8; ++nj) {
    int jl = nj * 16 + l15;
    sqc_l[nj] = sqc[jl];
    tc_l[nj]  = tc[jl];
  }

  float pm[16], nm[16], cmP[8], cmN[8];
#pragma unroll
  for (int s = 0; s < 16; ++s) { pm[s] = 0.f; nm[s] = __builtin_huge_valf(); }
#pragma unroll
  for (int nj = 0; nj < 8; ++nj) { cmP[nj] = 0.f; cmN[nj] = __builtin_huge_valf(); }

#pragma unroll
  for (int mi = 0; mi < 4; ++mi) {
#pragma unroll
    for (int r = 0; r < 4; ++r) {
      int il = wy * 64 + mi * 16 + quad * 4 + r;
      float si = sqr[il];
      int   ti = tr[il];
      int   s  = mi * 4 + r;
#pragma unroll
      for (int nj = 0; nj < 8; ++nj) {
        float d2 = fmaf(-2.f, acc[mi][nj][r], si + sqc_l[nj]);  // unclipped
        bool same = (ti == tc_l[nj]);
        // identity 0 for max is safe pre-clip: clip(max(0,...)) ==
        // max(clip(...)) outcome since the diagonal guarantees pmax>=1e-12.
        float selP = same ? d2 : 0.f;
        float selN = same ? __builtin_huge_valf() : d2;
        pm[s]   = fmaxf(pm[s], selP);
        nm[s]   = fminf(nm[s], selN);
        cmP[nj] = fmaxf(cmP[nj], selP);
        cmN[nj] = fminf(cmN[nj], selN);
      }
    }
  }

  // row-side halving butterfly across 16 lanes of each quad group
#pragma unroll
  for (int m = 8; m >= 1; m >>= 1) {
#pragma unroll
    for (int j = 0; j < m; ++j) {
      bool up = (l15 & m) != 0;
      float sp = up ? pm[j] : pm[j + m];
      float sn = up ? nm[j] : nm[j + m];
      float rp = __shfl_xor(sp, m);
      float rn = __shfl_xor(sn, m);
      float kp = up ? pm[j + m] : pm[j];
      float kn = up ? nm[j + m] : nm[j];
      pm[j] = fmaxf(kp, rp);
      nm[j] = fminf(kn, rn);
    }
  }
  {
    // clip BEFORE uint-ordered atomics (sign trick needs >= 0)
    int rowIdx = wy * 64 + ((l15 >> 2) << 4) + (quad << 2) + (l15 & 3);
    atomicMax(&pmL[rowIdx], __float_as_uint(fmaxf(pm[0], 1e-12f)));
    atomicMin(&nmL[rowIdx], __float_as_uint(fmaxf(nm[0], 1e-12f)));
  }

  // col-side: reduce across quads; each quad owns cols {quad, quad+4}*16+l15
#pragma unroll
  for (int nj = 0; nj < 8; ++nj) {
    cmP[nj] = fmaxf(cmP[nj], __shfl_xor(cmP[nj], 16));
    cmP[nj] = fmaxf(cmP[nj], __shfl_xor(cmP[nj], 32));
    cmN[nj] = fminf(cmN[nj], __shfl_xor(cmN[nj], 16));
    cmN[nj] = fminf(cmN[nj], __shfl_xor(cmN[nj], 32));
  }
  {
    float vP1 = (quad == 0) ? cmP[0] : (quad == 1) ? cmP[1] : (quad == 2) ? cmP[2] : cmP[3];
    float vN1 = (quad == 0) ? cmN[0] : (quad == 1) ? cmN[1] : (quad == 2) ? cmN[2] : cmN[3];
    float vP2 = (quad == 0) ? cmP[4] : (quad == 1) ? cmP[5] : (quad == 2) ? cmP[6] : cmP[7];
    float vN2 = (quad == 0) ? cmN[4] : (quad == 1) ? cmN[5] : (quad == 2) ? cmN[6] : cmN[7];
    int c1 = quad * 16 + l15, c2 = (quad + 4) * 16 + l15;
    atomicMax(&pmLc[c1], __float_as_uint(fmaxf(vP1, 1e-12f)));
    atomicMin(&nmLc[c1], __float_as_uint(fmaxf(vN1, 1e-12f)));
    atomicMax(&pmLc[c2], __float_as_uint(fmaxf(vP2, 1e-12f)));
    atomicMin(&nmLc[c2], __float_as_uint(fmaxf(vN2, 1e-12f)));
  }
  __syncthreads();

  // Global atomics with captured returns (sc0; completion at coherent point).
  unsigned keep;
  {
    unsigned o1 = atomicMax(&pmax[rowBase + t], pmL[t]);
    unsigned o2 = atomicMin(&nmin[rowBase + t], nmL[t]);
    keep = o1 ^ o2;
  }
  if (t < 128) {
    unsigned o3 = atomicMax(&pmax[colBase + t], pmLc[t]);
    unsigned o4 = atomicMin(&nmin[colBase + t], nmLc[t]);
    keep ^= o3 ^ o4;
  }
  asm volatile("" :: "v"(keep));  // keep returns live (no DCE of sc0)
  asm volatile("s_waitcnt vmcnt(0)" ::: "memory");
  __syncthreads();

  // arrival counter: all RMWs committed at the coherent point; no dirty
  // plain stores exist, so no wbl2 fence needed (the R3/R4 trap).
  if (t == 0) lastFlag = (atomicAdd(cnt, 1u) == NBLK - 1u) ? 1u : 0u;
  __syncthreads();

  if (lastFlag) {
    // ---- fused finish: agent-scope coherent loads, fully pipelined ----
    float lsum = 0.f, psum = 0.f;
#pragma unroll 4
    for (int i = t; i < N; i += 256) {
      unsigned pu = __hip_atomic_load(&pmax[i], __ATOMIC_RELAXED, __HIP_MEMORY_SCOPE_AGENT);
      unsigned nu = __hip_atomic_load(&nmin[i], __ATOMIC_RELAXED, __HIP_MEMORY_SCOPE_AGENT);
      float ap = sqrtf(__uint_as_float(pu));
      float an = sqrtf(__uint_as_float(nu));
      lsum += fmaxf(ap - an + MARGIN, 0.f);
      psum += (an > ap) ? 1.f : 0.f;
    }
#pragma unroll
    for (int o = 32; o > 0; o >>= 1) {
      lsum += __shfl_down(lsum, o);
      psum += __shfl_down(psum, o);
    }
    if ((t & 63) == 0) { fls[t >> 6] = lsum; fps[t >> 6] = psum; }
    __syncthreads();
    if (t == 0) {
      out[0] = (fls[0] + fls[1] + fls[2] + fls[3]) * (1.0f / (float)N);
      out[1] = (fps[0] + fps[1] + fps[2] + fps[3]) * (1.0f / (float)N);
    }
  }
}

extern "C" void kernel_launch(void* const* d_in, const int* in_sizes, int n_in,
                              void* d_out, int out_size, void* d_ws, size_t ws_size,
                              hipStream_t stream) {
  const float* X  = (const float*)d_in[0];
  const int* tgt  = (const int*)d_in[1];
  float* out      = (float*)d_out;

  char* ws = (char*)d_ws;
  unsigned short* Xb = (unsigned short*)ws;                    // 4 MiB
  float*    sq    = (float*)(ws + 4194304);                    // 32 KiB
  unsigned* pmax  = (unsigned*)(ws + 4194304 + 32768);         // 32 KiB
  unsigned* nmin  = (unsigned*)(ws + 4194304 + 65536);         // 32 KiB
  unsigned* cnt   = (unsigned*)(ws + 4194304 + 98304);         // 4 B

  prep_kernel<<<1024, 256, 0, stream>>>(X, Xb, sq, pmax, nmin, cnt);
  tile_kernel<<<NBLK, 256, 0, stream>>>(Xb, sq, tgt, pmax, nmin, cnt, out);
}

// Round 5
// 99.372 us; speedup vs baseline: 1.5598x; 1.0660x over previous
//
#include <hip/hip_runtime.h>
#include <hip/hip_bf16.h>

// TripletLoss, N=8192, D=256 fp32, targets in [0,128).
// out[0] = mean(relu(dist_ap - dist_an + 0.3)), out[1] = mean(dist_an > dist_ap)
// dist = sqrt(clip(sq_i + sq_j - 2 dot, 1e-12)); sqrt deferred (monotone);
// clipped d2 >= 0 so uint-bit order == float order -> atomicMax/Min unsigned.
//
// R10: restore TLP. R9 post-mortem: 256x128 tiles amortized per-block costs
// (score 113.8->105.9) but 4-wave blocks + 78.5KB LDS capped occupancy at
// 8 waves/CU (measured 14.6%) -> latency-bound collapse (VALUBusy 51->15%).
// Resource floor is ~8us; we pay 67us of exposed L2 latency.
//  - 512 threads / 8 waves per block, wave-tile 64x64 (acc[4][4], 16 MFMA +
//    8 ds_read + 3 DMA per wave per phase). Same 1056-block 256x128 cover.
//  - LDS 79.9KB -> 2 blocks/CU co-resident = 16 waves/CU (50% cap, 2x R9).
//  - VGPR: acc 64 + frags 32 + addr ~25 -> fits 128 = 4 waves/SIMD
//    (__launch_bounds__(512,4)).
//  - 1056 blocks / 512 slots = 2.06 rounds (clean quantization vs R9).
//  - Counted-vmcnt depth-2 prefetch, 3-deep buffers, single barrier per
//    phase (R8/R9 ledger, proven). vmcnt ladder: 3 x7, 0 x1.
//  - Fused finish via arrival counter (R8, proven: atomics-only coherence).

#define N 8192
#define D 256
#define MARGIN 0.3f
#define NBLK 1056  // sum over by=0..31 of (2*by+2) 256x128 tiles

typedef __bf16  bf16x8  __attribute__((ext_vector_type(8)));
typedef float   floatx4 __attribute__((ext_vector_type(4)));

__device__ __forceinline__ void load_lds16(const void* g, void* s) {
  __builtin_amdgcn_global_load_lds(
      (const __attribute__((address_space(1))) void*)g,
      (__attribute__((address_space(3))) void*)s, 16, 0, 0);
}

// ---------------- Kernel A: bf16 cast + row sq-norms + init ------------------
__global__ __launch_bounds__(256) void prep_kernel(
    const float* __restrict__ X, unsigned short* __restrict__ Xb,
    float* __restrict__ sq, unsigned* __restrict__ pmax, unsigned* __restrict__ nmin,
    unsigned* __restrict__ cnt) {
  const int t = threadIdx.x;
  if (blockIdx.x == 0 && t == 0) *cnt = 0u;  // re-poison arrival counter
  const int lane = t & 63, wave = t >> 6;
  const int row0 = blockIdx.x * 8 + wave * 2;
#pragma unroll
  for (int r = 0; r < 2; ++r) {
    const int row = row0 + r;
    float4 v = *reinterpret_cast<const float4*>(X + (size_t)row * D + lane * 4);
    ushort4 h;
    {
      __hip_bfloat16 b0 = __float2bfloat16(v.x), b1 = __float2bfloat16(v.y);
      __hip_bfloat16 b2 = __float2bfloat16(v.z), b3 = __float2bfloat16(v.w);
      h.x = *reinterpret_cast<unsigned short*>(&b0);
      h.y = *reinterpret_cast<unsigned short*>(&b1);
      h.z = *reinterpret_cast<unsigned short*>(&b2);
      h.w = *reinterpret_cast<unsigned short*>(&b3);
    }
    *reinterpret_cast<ushort4*>(Xb + (size_t)row * D + lane * 4) = h;
    float s = v.x * v.x + v.y * v.y + v.z * v.z + v.w * v.w;
#pragma unroll
    for (int o = 32; o > 0; o >>= 1) s += __shfl_down(s, o);
    if (lane == 0) {
      sq[row] = s;
      pmax[row] = 0u;
      nmin[row] = 0x7F800000u;  // +inf
    }
  }
}

// ---------------- Kernel B: 256x128 tiles, 8 waves + fused finish ------------
__global__ __launch_bounds__(512, 4) void tile_kernel(
    const unsigned short* __restrict__ Xb, const float* __restrict__ sq,
    const int* __restrict__ tgt, unsigned* __restrict__ pmax,
    unsigned* __restrict__ nmin, unsigned* __restrict__ cnt,
    float* __restrict__ out) {
  // T1: XCD-aware swizzle; NBLK % 8 == 0 (1056 = 8*132), bijective.
  const int hw = blockIdx.x;
  const int bi = (hw & 7) * (NBLK / 8) + (hw >> 3);

  // Triangle cover by 256-row x 128-col tiles: tile (by,bx) exists for
  // bx in [0, 2*by+2). Cumulative count C(by) = by*(by+1).
  int by = (int)((sqrtf(4.0f * (float)bi + 1.0f) - 1.0f) * 0.5f);
  while ((by + 1) * (by + 2) <= bi) ++by;
  while (by * (by + 1) > bi) --by;
  const int bx = bi - by * (by + 1);
  const int rowBase = by * 256, colBase = bx * 128;

  const int t = threadIdx.x;
  const int lane = t & 63, wave = t >> 6;
  const int wy = wave >> 1, wx = wave & 1;   // wave-tile 64x64
  const int quad = lane >> 4, l15 = lane & 15;

  // 3-deep rotating buffers: A 256x32 (16KB) x3, B 128x32 (8KB) x3
  __shared__ __align__(16) unsigned short As[3][256 * 32];  // 48 KB
  __shared__ __align__(16) unsigned short Bs[3][128 * 32];  // 24 KB
  __shared__ float sqr[256], sqc[128];
  __shared__ int   tr[256], tc[128];
  __shared__ unsigned pmL[256], nmL[256], pmLc[128], nmLc[128];
  __shared__ unsigned lastFlag;
  __shared__ float fls[8], fps[8];

  if (t < 256) {
    sqr[t] = sq[rowBase + t]; tr[t] = tgt[rowBase + t];
    pmL[t] = 0u; nmL[t] = 0x7F800000u;
  } else if (t < 384) {
    int u = t - 256;
    sqc[u] = sq[colBase + u]; tc[u] = tgt[colBase + u];
    pmLc[u] = 0u; nmLc[u] = 0x7F800000u;
  }

  const unsigned short* Ag = Xb + (size_t)rowBase * D;
  const unsigned short* Bg = Xb + (size_t)colBase * D;

  // DMA source pre-swizzle (both sides or neither): LDS slot s of row holds
  // global chunk s ^ f(row), f(x) = ((x&3) + (x>>2)) & 3; f invariant under
  // row +128 and +16/+64 multiples -> one base + immediates everywhere.
  const int r0 = t >> 2;                              // 0..127
  const int cA = (t & 3) ^ ((r0 + (r0 >> 2)) & 3);
  const int g0 = r0 * D + cA * 8;                     // elements
  const int wl = wave * 1024;                         // wave-uniform LDS base

  // ds_read bases (swizzled); per-mi/nj/buffer offsets are immediates.
  const int fq  = (l15 + (l15 >> 2)) & 3;
  const int aA0 = ((wy * 64 + l15) * 4 + (quad ^ fq)) * 16;  // +mi*1024 +buf*16384
  const int bA0 = ((wx * 64 + l15) * 4 + (quad ^ fq)) * 16;  // +nj*1024 +buf*8192
  const char* AsB = (const char*)As;
  const char* BsB = (const char*)Bs;

  floatx4 acc[4][4];
#pragma unroll
  for (int mi = 0; mi < 4; ++mi)
#pragma unroll
    for (int nj = 0; nj < 4; ++nj)
      acc[mi][nj] = (floatx4){0.f, 0.f, 0.f, 0.f};

  // 3 DMA loads/thread/phase: A rows r0, r0+128; B row r0 (512 thr = 128 rows)
#define ISSUE_DMA(ph) do {                                                   \
    const int ko_ = (ph) * 32;                                               \
    char* an_ = (char*)As[(ph) % 3];                                         \
    char* bn_ = (char*)Bs[(ph) % 3];                                         \
    load_lds16(Ag + g0 + ko_,                an_ + wl);                      \
    load_lds16(Ag + g0 + 128 * D + ko_,      an_ + wl + 8192);               \
    load_lds16(Bg + g0 + ko_,                bn_ + wl);                      \
  } while (0)

  // Single barrier per phase (R8/R9 ledger):
  //  * vmcnt(VM) BEFORE barrier drains this wave's phase-k DMA group (3
  //    loads; group k+1 still outstanding -> VM=3; tail VM=0). All waves
  //    drained before any exits => tile k%3 valid cross-wave at exit.
  //  * ISSUE k+2 after the barrier overwrites buf (k-1)%3; every wave
  //    secured its phase-(k-1) ds_reads (lgkmcnt(0)) before arriving.
#define PHASE(kk, VM) do {                                                   \
    asm volatile("s_waitcnt vmcnt(" #VM ")" ::: "memory");                   \
    __builtin_amdgcn_s_barrier();                                            \
    __builtin_amdgcn_sched_barrier(0);                                       \
    const char* ab_ = AsB + ((kk) % 3) * 16384;                              \
    const char* bb_ = BsB + ((kk) % 3) * 8192;                               \
    bf16x8 a_[4], b_[4];                                                     \
    _Pragma("unroll")                                                        \
    for (int mi = 0; mi < 4; ++mi)                                           \
      a_[mi] = *reinterpret_cast<const bf16x8*>(ab_ + aA0 + mi * 1024);      \
    _Pragma("unroll")                                                        \
    for (int nj = 0; nj < 4; ++nj)                                           \
      b_[nj] = *reinterpret_cast<const bf16x8*>(bb_ + bA0 + nj * 1024);      \
    if ((kk) < 6) ISSUE_DMA((kk) + 2);                                       \
    asm volatile("s_waitcnt lgkmcnt(0)" ::: "memory");                       \
    __builtin_amdgcn_sched_barrier(0);                                       \
    __builtin_amdgcn_s_setprio(1);                                           \
    _Pragma("unroll")                                                        \
    for (int mi = 0; mi < 4; ++mi)                                           \
      _Pragma("unroll")                                                      \
      for (int nj = 0; nj < 4; ++nj)                                         \
        acc[mi][nj] = __builtin_amdgcn_mfma_f32_16x16x32_bf16(               \
            a_[mi], b_[nj], acc[mi][nj], 0, 0, 0);                           \
    __builtin_amdgcn_s_setprio(0);                                           \
    __builtin_amdgcn_sched_barrier(0);                                       \
  } while (0)

  // prologue: phases 0 and 1 in flight (6 loads/thread outstanding)
  ISSUE_DMA(0);
  ISSUE_DMA(1);

  PHASE(0, 3);
  PHASE(1, 3);
  PHASE(2, 3);
  PHASE(3, 3);
  PHASE(4, 3);
  PHASE(5, 3);
  PHASE(6, 3);
  PHASE(7, 0);

#undef PHASE
#undef ISSUE_DMA

  __syncthreads();

  // ---- two-sided epilogue on UNclipped d2 (clip deferred to pushes) ----
  float sqc_l[4]; int tc_l[4];
#pragma unroll
  for (int nj = 0; nj < 4; ++nj) {
    int jl = wx * 64 + nj * 16 + l15;
    sqc_l[nj] = sqc[jl];
    tc_l[nj]  = tc[jl];
  }

  float pm[16], nm[16], cmP[4], cmN[4];
#pragma unroll
  for (int s = 0; s < 16; ++s) { pm[s] = 0.f; nm[s] = __builtin_huge_valf(); }
#pragma unroll
  for (int nj = 0; nj < 4; ++nj) { cmP[nj] = 0.f; cmN[nj] = __builtin_huge_valf(); }

#pragma unroll
  for (int mi = 0; mi < 4; ++mi) {
#pragma unroll
    for (int r = 0; r < 4; ++r) {
      int il = wy * 64 + mi * 16 + quad * 4 + r;
      float si = sqr[il];
      int   ti = tr[il];
      int   s  = mi * 4 + r;
#pragma unroll
      for (int nj = 0; nj < 4; ++nj) {
        float d2 = fmaf(-2.f, acc[mi][nj][r], si + sqc_l[nj]);  // unclipped
        bool same = (ti == tc_l[nj]);
        // 0-identity pre-clip is safe for max: diagonal guarantees the true
        // pmax >= 1e-12, and clip is re-applied before the ordered atomics.
        float selP = same ? d2 : 0.f;
        float selN = same ? __builtin_huge_valf() : d2;
        pm[s]   = fmaxf(pm[s], selP);
        nm[s]   = fminf(nm[s], selN);
        cmP[nj] = fmaxf(cmP[nj], selP);
        cmN[nj] = fminf(cmN[nj], selN);
      }
    }
  }

  // row-side halving butterfly across 16 lanes of each quad group
#pragma unroll
  for (int m = 8; m >= 1; m >>= 1) {
#pragma unroll
    for (int j = 0; j < m; ++j) {
      bool up = (l15 & m) != 0;
      float sp = up ? pm[j] : pm[j + m];
      float sn = up ? nm[j] : nm[j + m];
      float rp = __shfl_xor(sp, m);
      float rn = __shfl_xor(sn, m);
      float kp = up ? pm[j + m] : pm[j];
      float kn = up ? nm[j + m] : nm[j];
      pm[j] = fmaxf(kp, rp);
      nm[j] = fminf(kn, rn);
    }
  }
  {
    // clip BEFORE uint-ordered atomics (sign trick needs >= 0)
    int rowIdx = wy * 64 + ((l15 >> 2) << 4) + (quad << 2) + (l15 & 3);
    atomicMax(&pmL[rowIdx], __float_as_uint(fmaxf(pm[0], 1e-12f)));
    atomicMin(&nmL[rowIdx], __float_as_uint(fmaxf(nm[0], 1e-12f)));
  }

  // col-side: reduce across quads
#pragma unroll
  for (int nj = 0; nj < 4; ++nj) {
    cmP[nj] = fmaxf(cmP[nj], __shfl_xor(cmP[nj], 16));
    cmP[nj] = fmaxf(cmP[nj], __shfl_xor(cmP[nj], 32));
    cmN[nj] = fminf(cmN[nj], __shfl_xor(cmN[nj], 16));
    cmN[nj] = fminf(cmN[nj], __shfl_xor(cmN[nj], 32));
  }
  {
    float vP = (quad == 0) ? cmP[0] : (quad == 1) ? cmP[1] : (quad == 2) ? cmP[2] : cmP[3];
    float vN = (quad == 0) ? cmN[0] : (quad == 1) ? cmN[1] : (quad == 2) ? cmN[2] : cmN[3];
    int colIdx = wx * 64 + quad * 16 + l15;
    atomicMax(&pmLc[colIdx], __float_as_uint(fmaxf(vP, 1e-12f)));
    atomicMin(&nmLc[colIdx], __float_as_uint(fmaxf(vN, 1e-12f)));
  }
  __syncthreads();

  // Global atomics with captured returns (sc0; completion at coherent point).
  unsigned keep = 0u;
  if (t < 256) {
    unsigned o1 = atomicMax(&pmax[rowBase + t], pmL[t]);
    unsigned o2 = atomicMin(&nmin[rowBase + t], nmL[t]);
    keep = o1 ^ o2;
  } else if (t < 384) {
    int u = t - 256;
    unsigned o3 = atomicMax(&pmax[colBase + u], pmLc[u]);
    unsigned o4 = atomicMin(&nmin[colBase + u], nmLc[u]);
    keep = o3 ^ o4;
  }
  asm volatile("" :: "v"(keep));  // keep returns live (no DCE of sc0)
  asm volatile("s_waitcnt vmcnt(0)" ::: "memory");
  __syncthreads();

  // arrival counter: all RMWs committed at the coherent point; no dirty
  // plain stores exist, so no wbl2 fence needed (the R3/R4 trap).
  if (t == 0) lastFlag = (atomicAdd(cnt, 1u) == NBLK - 1u) ? 1u : 0u;
  __syncthreads();

  if (lastFlag) {
    // ---- fused finish: agent-scope coherent loads, fully pipelined ----
    float lsum = 0.f, psum = 0.f;
#pragma unroll 4
    for (int i = t; i < N; i += 512) {
      unsigned pu = __hip_atomic_load(&pmax[i], __ATOMIC_RELAXED, __HIP_MEMORY_SCOPE_AGENT);
      unsigned nu = __hip_atomic_load(&nmin[i], __ATOMIC_RELAXED, __HIP_MEMORY_SCOPE_AGENT);
      float ap = sqrtf(__uint_as_float(pu));
      float an = sqrtf(__uint_as_float(nu));
      lsum += fmaxf(ap - an + MARGIN, 0.f);
      psum += (an > ap) ? 1.f : 0.f;
    }
#pragma unroll
    for (int o = 32; o > 0; o >>= 1) {
      lsum += __shfl_down(lsum, o);
      psum += __shfl_down(psum, o);
    }
    if ((t & 63) == 0) { fls[t >> 6] = lsum; fps[t >> 6] = psum; }
    __syncthreads();
    if (t == 0) {
      float L = 0.f, P = 0.f;
#pragma unroll
      for (int w = 0; w < 8; ++w) { L += fls[w]; P += fps[w]; }
      out[0] = L * (1.0f / (float)N);
      out[1] = P * (1.0f / (float)N);
    }
  }
}

extern "C" void kernel_launch(void* const* d_in, const int* in_sizes, int n_in,
                              void* d_out, int out_size, void* d_ws, size_t ws_size,
                              hipStream_t stream) {
  const float* X  = (const float*)d_in[0];
  const int* tgt  = (const int*)d_in[1];
  float* out      = (float*)d_out;

  char* ws = (char*)d_ws;
  unsigned short* Xb = (unsigned short*)ws;                    // 4 MiB
  float*    sq    = (float*)(ws + 4194304);                    // 32 KiB
  unsigned* pmax  = (unsigned*)(ws + 4194304 + 32768);         // 32 KiB
  unsigned* nmin  = (unsigned*)(ws + 4194304 + 65536);         // 32 KiB
  unsigned* cnt   = (unsigned*)(ws + 4194304 + 98304);         // 4 B

  prep_kernel<<<1024, 256, 0, stream>>>(X, Xb, sq, pmax, nmin, cnt);
  tile_kernel<<<NBLK, 512, 0, stream>>>(Xb, sq, tgt, pmax, nmin, cnt, out);
}